// Round 11
// baseline (336.970 us; speedup 1.0000x reference)
//
#include <hip/hip_runtime.h>
#include <hip/hip_cooperative_groups.h>
#include <stdint.h>

namespace cg = cooperative_groups;

// out[i] = max((cnts[g_i] + h[g_i]) / (total + N), 0.01),
//   g_i = gdict[i], h[s] = #{ t : gdict[flatten_label[t]] == s }.
//
// Exact data-dependent shortcut (round 10, validated): clip floor 0.01*T needs
// ~167K counts in one slot (5000x the mean 33.5). Per coarse bucket B(l)=l>>12,
// h[gdict[l]] <= bucket_count[B(l)] when the slot has a unique contributor;
// fp add/div monotone => ub <= 0.01 implies out == 0.01 bit-exactly. A guarded
// exact fallback (device atomics) covers conflicted/undecided slots.
//
// Round 11: fuse all 7 dispatches into ONE cooperative kernel (grid.sync
// phase barriers) - removes ~6 graph-node gaps + intermediate traffic.
// REPL=16 LDS sub-histograms: bank=(16b+r)%32 -> each 4-lane r-group covers 2
// banks => ~2-way conflicts (free, m136).

#define FBITS     12
#define NBUCK_MAX 256
#define GRID_F    1024     // cooperative grid: 4 blocks/CU guaranteed resident
#define REPL16    16
#define REPL      4        // fallback path (round-10 kA)
#define GRID_A    2048

static inline size_t align256(size_t x) { return (x + 255) & ~(size_t)255; }

// ======================= fused cooperative kernel =======================
__global__ __launch_bounds__(256) void fused(const int* __restrict__ labels,
                                             const int* __restrict__ gdict,
                                             const float* __restrict__ cnts,
                                             const float* __restrict__ total,
                                             float* __restrict__ out,
                                             uint32_t* __restrict__ flag,
                                             uint32_t* __restrict__ bc,        // [nbuck]
                                             uint8_t*  __restrict__ conflicted,// [nbins]
                                             uint32_t* __restrict__ slotsum,   // [nbins]
                                             uint32_t* __restrict__ marker,    // [nbins]
                                             uint32_t* __restrict__ pbc,       // [GRID_F][nbuck]
                                             int n, int llen, int nbins, int nbuck,
                                             float nf) {
    cg::grid_group grid = cg::this_grid();
    __shared__ uint32_t h[REPL16 * NBUCK_MAX];   // 16 KB
    __shared__ uint32_t wsum[4];
    int tid = threadIdx.x, bk = blockIdx.x;
    int gtid = bk * 256 + tid;
    int gstride = gridDim.x * 256;

    // ---------- P0: zero small state | marker scatter | coarse histogram ----------
    if (gtid == 0) *flag = 0u;
    for (int i = gtid; i < nbins; i += gstride) conflicted[i] = 0;
    for (int l = gtid; l < llen; l += gstride) {
        uint32_t g = (uint32_t)gdict[l];
        if (g < (uint32_t)nbins) marker[g] = (uint32_t)l + 1u;  // last-writer-wins
    }

    for (int j = tid; j < REPL16 * nbuck; j += 256) h[j] = 0;
    __syncthreads();

    int r = tid & (REPL16 - 1);
    const int4* l4 = (const int4*)labels;
    int n4 = n >> 2;
    for (int i = gtid; i < n4; i += gstride) {
        int4 q = l4[i];
        atomicAdd(&h[(((uint32_t)q.x) >> FBITS) * REPL16 + r], 1u);
        atomicAdd(&h[(((uint32_t)q.y) >> FBITS) * REPL16 + r], 1u);
        atomicAdd(&h[(((uint32_t)q.z) >> FBITS) * REPL16 + r], 1u);
        atomicAdd(&h[(((uint32_t)q.w) >> FBITS) * REPL16 + r], 1u);
    }
    for (int i = (n4 << 2) + gtid; i < n; i += gstride)
        atomicAdd(&h[(((uint32_t)labels[i]) >> FBITS) * REPL16 + r], 1u);
    __syncthreads();

    for (int b = tid; b < nbuck; b += 256) {
        uint32_t s = 0;
        #pragma unroll
        for (int k = 0; k < REPL16; ++k) s += h[b * REPL16 + k];
        pbc[(size_t)bk * nbuck + b] = s;
    }

    grid.sync();

    // ---------- P1: bc reduce (blocks < nbuck) | conflict detect (all) ----------
    if (bk < nbuck) {
        uint32_t s = 0;
        for (int j = tid; j < (int)gridDim.x; j += 256)
            s += pbc[(size_t)j * nbuck + bk];
        for (int o = 32; o > 0; o >>= 1) s += __shfl_down(s, o, 64);
        if ((tid & 63) == 0) wsum[tid >> 6] = s;
        __syncthreads();
        if (tid == 0) bc[bk] = wsum[0] + wsum[1] + wsum[2] + wsum[3];
    }
    for (int l = gtid; l < llen; l += gstride) {
        uint32_t g = (uint32_t)gdict[l];
        if (g < (uint32_t)nbins && marker[g] != (uint32_t)l + 1u)
            conflicted[g] = 1;   // benign same-value race
    }

    grid.sync();

    // ---------- P2: decide via upper bound ----------
    float T = total[0] + nf;
    bool undecided = false;
    for (int i = gtid; i < llen; i += gstride) {
        int gi = gdict[i];
        uint32_t g = (uint32_t)min(max(gi, 0), nbins - 1);   // jax gather clamp
        float v = (cnts[g] + (float)bc[i >> FBITS]) / T;
        bool dec = ((uint32_t)gi < (uint32_t)nbins) && (!conflicted[g]) && (v <= 0.01f);
        if (dec) out[i] = 0.01f;
        else undecided = true;
    }
    if (undecided) atomicOr(flag, 1u);   // rare

    grid.sync();

    // ---------- P3: guarded exact fallback (uniform branch across grid) ----------
    if (__hip_atomic_load(flag, __ATOMIC_RELAXED, __HIP_MEMORY_SCOPE_AGENT) != 0u) {
        for (int i = gtid; i < nbins; i += gstride) slotsum[i] = 0u;
        grid.sync();
        for (int i = gtid; i < n; i += gstride) {
            uint32_t g = (uint32_t)gdict[labels[i]];
            if (g < (uint32_t)nbins) atomicAdd(&slotsum[g], 1u);
        }
        grid.sync();
        for (int i = gtid; i < llen; i += gstride) {
            int gi = gdict[i];
            uint32_t g = (uint32_t)min(max(gi, 0), nbins - 1);
            out[i] = fmaxf((cnts[g] + (float)slotsum[g]) / T, 0.01f);
        }
    }
}

// ======================= round-10 fallback pipeline =======================

__global__ __launch_bounds__(256) void zero_ws(int4* __restrict__ p, int n16) {
    int tid = blockIdx.x * 256 + threadIdx.x;
    int stride = gridDim.x * 256;
    int4 z = {0, 0, 0, 0};
    for (int i = tid; i < n16; i += stride) p[i] = z;
}

__global__ __launch_bounds__(256) void kA_coarse(const int* __restrict__ labels,
                                                 const int* __restrict__ gdict,
                                                 uint32_t* __restrict__ pbc,
                                                 uint32_t* __restrict__ marker,
                                                 int n, int llen, int nbins, int nbuck) {
    __shared__ uint32_t h[REPL * NBUCK_MAX];
    int tid = threadIdx.x, bk = blockIdx.x;
    int gstride = gridDim.x * 256;
    for (int l = bk * 256 + tid; l < llen; l += gstride) {
        uint32_t g = (uint32_t)gdict[l];
        if (g < (uint32_t)nbins) marker[g] = (uint32_t)l + 1u;
    }
    for (int j = tid; j < REPL * nbuck; j += 256) h[j] = 0;
    __syncthreads();
    int r = tid & (REPL - 1);
    const int4* l4 = (const int4*)labels;
    int n4 = n >> 2;
    for (int i = bk * 256 + tid; i < n4; i += gstride) {
        int4 q = l4[i];
        atomicAdd(&h[(((uint32_t)q.x) >> FBITS) * REPL + r], 1u);
        atomicAdd(&h[(((uint32_t)q.y) >> FBITS) * REPL + r], 1u);
        atomicAdd(&h[(((uint32_t)q.z) >> FBITS) * REPL + r], 1u);
        atomicAdd(&h[(((uint32_t)q.w) >> FBITS) * REPL + r], 1u);
    }
    for (int i = (n4 << 2) + bk * 256 + tid; i < n; i += gstride)
        atomicAdd(&h[(((uint32_t)labels[i]) >> FBITS) * REPL + r], 1u);
    __syncthreads();
    for (int b = tid; b < nbuck; b += 256)
        pbc[(size_t)bk * nbuck + b] =
            h[b * REPL] + h[b * REPL + 1] + h[b * REPL + 2] + h[b * REPL + 3];
}

__global__ __launch_bounds__(256) void kB_reduce(const uint32_t* __restrict__ pbc,
                                                 uint32_t* __restrict__ bc,
                                                 int nblocks, int nbuck) {
    __shared__ uint32_t wsum[4];
    int b = blockIdx.x, tid = threadIdx.x;
    uint32_t s = 0;
    for (int j = tid; j < nblocks; j += 256) s += pbc[(size_t)j * nbuck + b];
    for (int o = 32; o > 0; o >>= 1) s += __shfl_down(s, o, 64);
    if ((tid & 63) == 0) wsum[tid >> 6] = s;
    __syncthreads();
    if (tid == 0) bc[b] = wsum[0] + wsum[1] + wsum[2] + wsum[3];
}

__global__ __launch_bounds__(256) void kC_conf(const int* __restrict__ gdict,
                                               const uint32_t* __restrict__ marker,
                                               uint8_t* __restrict__ conflicted,
                                               int llen, int nbins) {
    int l = blockIdx.x * 256 + threadIdx.x;
    if (l >= llen) return;
    uint32_t g = (uint32_t)gdict[l];
    if (g < (uint32_t)nbins && marker[g] != (uint32_t)l + 1u) conflicted[g] = 1;
}

__global__ __launch_bounds__(256) void kD_decide(const int* __restrict__ gdict,
                                                 const float* __restrict__ cnts,
                                                 const uint32_t* __restrict__ bc,
                                                 const uint8_t* __restrict__ conflicted,
                                                 const float* __restrict__ total,
                                                 float* __restrict__ out,
                                                 uint32_t* __restrict__ flag,
                                                 int llen, int nbins, float nf) {
    int i = blockIdx.x * 256 + threadIdx.x;
    if (i >= llen) return;
    int gi = gdict[i];
    uint32_t g = (uint32_t)min(max(gi, 0), nbins - 1);
    float T = total[0] + nf;
    float v = (cnts[g] + (float)bc[i >> FBITS]) / T;
    bool dec = ((uint32_t)gi < (uint32_t)nbins) && (!conflicted[g]) && (v <= 0.01f);
    if (dec) out[i] = 0.01f;
    else     atomicOr(flag, 1u);
}

__global__ void histG(const uint32_t* __restrict__ flag,
                      const int* __restrict__ labels,
                      const int* __restrict__ gdict,
                      unsigned int* __restrict__ slotsum, int n, int nbins) {
    if (*flag == 0u) return;
    int tid = blockIdx.x * blockDim.x + threadIdx.x;
    int stride = gridDim.x * blockDim.x;
    for (int i = tid; i < n; i += stride) {
        uint32_t g = (uint32_t)gdict[labels[i]];
        if (g < (uint32_t)nbins) atomicAdd(&slotsum[g], 1u);
    }
}

__global__ __launch_bounds__(256) void p5G(const uint32_t* __restrict__ flag,
                                           const int* __restrict__ gdict,
                                           const float* __restrict__ cnts,
                                           const uint32_t* __restrict__ slotsum,
                                           const float* __restrict__ total,
                                           float* __restrict__ out,
                                           int llen, int nbins, float nf) {
    if (*flag == 0u) return;
    int i = blockIdx.x * 256 + threadIdx.x;
    if (i >= llen) return;
    int gi = gdict[i];
    uint32_t g = (uint32_t)min(max(gi, 0), nbins - 1);
    out[i] = fmaxf((cnts[g] + (float)slotsum[g]) / (total[0] + nf), 0.01f);
}

// ======================= tier-3 =======================
__global__ void hist_atomic(const int* __restrict__ labels,
                            const int* __restrict__ gdict,
                            unsigned int* __restrict__ ws, int n, int nbins) {
    int tid = blockIdx.x * blockDim.x + threadIdx.x;
    int stride = gridDim.x * blockDim.x;
    for (int i = tid; i < n; i += stride) {
        uint32_t g = (uint32_t)gdict[labels[i]];
        if (g < (uint32_t)nbins) atomicAdd(&ws[g], 1u);
    }
}

__global__ __launch_bounds__(256) void p5_simple(const int* __restrict__ gdict,
                                                 const float* __restrict__ cnts,
                                                 const uint32_t* __restrict__ slotsum,
                                                 const float* __restrict__ total,
                                                 float* __restrict__ out,
                                                 int llen, int nbins, float nf) {
    int i = blockIdx.x * 256 + threadIdx.x;
    if (i < llen) {
        int gi = gdict[i];
        uint32_t g = (uint32_t)min(max(gi, 0), nbins - 1);
        out[i] = fmaxf((cnts[g] + (float)slotsum[g]) / (total[0] + nf), 0.01f);
    }
}

extern "C" void kernel_launch(void* const* d_in, const int* in_sizes, int n_in,
                              void* d_out, int out_size, void* d_ws, size_t ws_size,
                              hipStream_t stream) {
    const int* gdict   = (const int*)d_in[0];
    const int* labels  = (const int*)d_in[1];
    const float* cnts  = (const float*)d_in[3];
    const float* total = (const float*)d_in[4];
    float* out = (float*)d_out;

    int llen  = in_sizes[0];
    int n     = in_sizes[1];
    int nbins = in_sizes[3];
    int nbuck = ((llen - 1) >> FBITS) + 1;
    float nf  = (float)n;

    uint8_t* ws8 = (uint8_t*)d_ws;

    // layout: [flag][bc][conflicted][slotsum][marker][pbc]  (fused zeroes what it needs)
    size_t o_flag = 0;
    size_t o_bc   = 256;
    size_t o_conf = align256(o_bc + (size_t)nbuck * 4);
    size_t o_slot = align256(o_conf + (size_t)nbins);
    size_t o_mark = align256(o_slot + (size_t)nbins * 4);
    size_t o_pbc  = align256(o_mark + (size_t)nbins * 4);
    size_t needF  = o_pbc + (size_t)GRID_F * nbuck * 4;   // fused (GRID_F rows)
    size_t needA  = o_pbc + (size_t)GRID_A * nbuck * 4;   // fallback (GRID_A rows)

    uint32_t* flag       = (uint32_t*)(ws8 + o_flag);
    uint32_t* bc         = (uint32_t*)(ws8 + o_bc);
    uint8_t*  conflicted = (uint8_t*)(ws8 + o_conf);
    uint32_t* slotsum    = (uint32_t*)(ws8 + o_slot);
    uint32_t* marker     = (uint32_t*)(ws8 + o_mark);
    uint32_t* pbc        = (uint32_t*)(ws8 + o_pbc);

    bool done = false;

    if (nbuck <= NBUCK_MAX && needF <= ws_size) {
        void* args[] = {
            (void*)&labels, (void*)&gdict, (void*)&cnts, (void*)&total, (void*)&out,
            (void*)&flag, (void*)&bc, (void*)&conflicted, (void*)&slotsum,
            (void*)&marker, (void*)&pbc,
            (void*)&n, (void*)&llen, (void*)&nbins, (void*)&nbuck, (void*)&nf
        };
        hipError_t e = hipLaunchCooperativeKernel((const void*)fused,
                                                  dim3(GRID_F), dim3(256),
                                                  args, 0, stream);
        done = (e == hipSuccess);
        if (!done) (void)hipGetLastError();
    }

    if (!done && nbuck <= NBUCK_MAX && needA <= ws_size) {
        // round-10 proven 7-node path
        int lblocks = (llen + 255) / 256;
        size_t z_end = o_mark;  // zero flag|bc|conflicted|slotsum
        hipLaunchKernelGGL(zero_ws, dim3(1024), dim3(256), 0, stream,
                           (int4*)ws8, (int)(z_end / 16));
        hipLaunchKernelGGL(kA_coarse, dim3(GRID_A), dim3(256), 0, stream,
                           labels, gdict, pbc, marker, n, llen, nbins, nbuck);
        hipLaunchKernelGGL(kB_reduce, dim3(nbuck), dim3(256), 0, stream,
                           pbc, bc, GRID_A, nbuck);
        hipLaunchKernelGGL(kC_conf, dim3(lblocks), dim3(256), 0, stream,
                           gdict, marker, conflicted, llen, nbins);
        hipLaunchKernelGGL(kD_decide, dim3(lblocks), dim3(256), 0, stream,
                           gdict, cnts, bc, conflicted, total, out, flag,
                           llen, nbins, nf);
        hipLaunchKernelGGL(histG, dim3(2048), dim3(256), 0, stream,
                           flag, labels, gdict, (unsigned int*)slotsum, n, nbins);
        hipLaunchKernelGGL(p5G, dim3(lblocks), dim3(256), 0, stream,
                           flag, gdict, cnts, slotsum, total, out, llen, nbins, nf);
        done = true;
    }

    if (!done) {
        uint32_t* ss = (uint32_t*)ws8;
        hipMemsetAsync(ss, 0, (size_t)nbins * 4, stream);
        hipLaunchKernelGGL(hist_atomic, dim3(2048), dim3(256), 0, stream,
                           labels, gdict, (unsigned int*)ss, n, nbins);
        hipLaunchKernelGGL(p5_simple, dim3((llen + 255) / 256), dim3(256), 0, stream,
                           gdict, cnts, ss, total, out, llen, nbins, nf);
    }
}

// Round 12
// 28.817 us; speedup vs baseline: 11.6933x; 11.6933x over previous
//
#include <hip/hip_runtime.h>
#include <stdint.h>

// out[i] = max((cnts[g_i] + h[g_i]) / (total + N), 0.01),
//   g_i = gdict[i], h[s] = #{ t : gdict[flatten_label[t]] == s }.
//
// Exact data-dependent shortcut (round 10, validated): the clip floor 0.01*T
// needs ~167K counts in one slot (5000x the 33.5 mean). Per coarse bucket
// B(l)=l>>12, h[gdict[l]] <= bucket_count[B(l)] when the slot has a unique
// contributor; fp add/div monotone => ub <= 0.01 implies out == 0.01
// bit-exactly. Flag-gated exact fallback covers conflicted/undecided slots.
//
// Hard-won gfx950 facts:
//  - global atomics are memory-side write-through (~32B each) at ANY scope
//    (rounds 1/6) -> fallback only.
//  - cooperative grid.sync() ~100us each on 8-XCD MI355X (round 11: 3 syncs
//    = 328us for 25us of work) -> use kernel-launch boundaries for ordering.
//  - rocclr fillBufferAligned is slow (tiny fixed grid) -> zero in-kernel.
//
// Round 12: 5 dispatches (was 7): kA absorbs zeroing of flag+conflicted,
// kBC fuses reduce+conflict-detect, kD absorbs slotsum zeroing.

#define FBITS     12
#define NBUCK_MAX 256
#define REPL      4
#define GRID_A    2048

static inline size_t align256(size_t x) { return (x + 255) & ~(size_t)255; }

// ---- kA: zero flag/conflicted | marker scatter | coarse label histogram ----
__global__ __launch_bounds__(256) void kA_coarse(const int* __restrict__ labels,
                                                 const int* __restrict__ gdict,
                                                 uint32_t* __restrict__ pbc,    // [GRID_A][nbuck]
                                                 uint32_t* __restrict__ marker, // [nbins] (never pre-zeroed)
                                                 uint8_t*  __restrict__ conflicted, // [nbins]
                                                 uint32_t* __restrict__ flag,
                                                 int n, int llen, int nbins, int nbuck) {
    __shared__ uint32_t h[REPL * NBUCK_MAX];   // 4 KB
    int tid = threadIdx.x, bk = blockIdx.x;
    int gtid = bk * 256 + tid;
    int gstride = gridDim.x * 256;

    if (gtid == 0) *flag = 0u;
    for (int i = gtid; i < nbins; i += gstride) conflicted[i] = 0;
    // winner marking: every in-image slot rewritten every call (last-writer-wins)
    for (int l = gtid; l < llen; l += gstride) {
        uint32_t g = (uint32_t)gdict[l];
        if (g < (uint32_t)nbins) marker[g] = (uint32_t)l + 1u;
    }

    for (int j = tid; j < REPL * nbuck; j += 256) h[j] = 0;
    __syncthreads();

    int r = tid & (REPL - 1);
    const int4* l4 = (const int4*)labels;
    int n4 = n >> 2;
    for (int i = gtid; i < n4; i += gstride) {
        int4 q = l4[i];
        atomicAdd(&h[(((uint32_t)q.x) >> FBITS) * REPL + r], 1u);
        atomicAdd(&h[(((uint32_t)q.y) >> FBITS) * REPL + r], 1u);
        atomicAdd(&h[(((uint32_t)q.z) >> FBITS) * REPL + r], 1u);
        atomicAdd(&h[(((uint32_t)q.w) >> FBITS) * REPL + r], 1u);
    }
    for (int i = (n4 << 2) + gtid; i < n; i += gstride)
        atomicAdd(&h[(((uint32_t)labels[i]) >> FBITS) * REPL + r], 1u);
    __syncthreads();

    for (int b = tid; b < nbuck; b += 256)
        pbc[(size_t)bk * nbuck + b] =
            h[b * REPL] + h[b * REPL + 1] + h[b * REPL + 2] + h[b * REPL + 3];
}

// ---- kBC: bucket reduce (blocks < nbuck) | conflict detect (all blocks) ----
__global__ __launch_bounds__(256) void kBC(const uint32_t* __restrict__ pbc,
                                           uint32_t* __restrict__ bc,
                                           const int* __restrict__ gdict,
                                           const uint32_t* __restrict__ marker,
                                           uint8_t* __restrict__ conflicted,
                                           int nblocks, int nbuck, int llen, int nbins) {
    __shared__ uint32_t wsum[4];
    int tid = threadIdx.x, bk = blockIdx.x;
    int gstride = gridDim.x * 256;

    if (bk < nbuck) {
        uint32_t s = 0;
        for (int j = tid; j < nblocks; j += 256) s += pbc[(size_t)j * nbuck + bk];
        for (int o = 32; o > 0; o >>= 1) s += __shfl_down(s, o, 64);
        if ((tid & 63) == 0) wsum[tid >> 6] = s;
        __syncthreads();
        if (tid == 0) bc[bk] = wsum[0] + wsum[1] + wsum[2] + wsum[3];
    }
    for (int l = bk * 256 + tid; l < llen; l += gstride) {
        uint32_t g = (uint32_t)gdict[l];
        if (g < (uint32_t)nbins && marker[g] != (uint32_t)l + 1u)
            conflicted[g] = 1;   // benign same-value race
    }
}

// ---- kD: zero slotsum (read only by later histG) | decide via upper bound ----
__global__ __launch_bounds__(256) void kD_decide(const int* __restrict__ gdict,
                                                 const float* __restrict__ cnts,
                                                 const uint32_t* __restrict__ bc,
                                                 const uint8_t* __restrict__ conflicted,
                                                 const float* __restrict__ total,
                                                 float* __restrict__ out,
                                                 uint32_t* __restrict__ flag,
                                                 uint32_t* __restrict__ slotsum,
                                                 int llen, int nbins, float nf) {
    int tid = threadIdx.x, bk = blockIdx.x;
    int gtid = bk * 256 + tid;
    int gstride = gridDim.x * 256;

    for (int i = gtid; i < nbins; i += gstride) slotsum[i] = 0u;

    bool undecided = false;
    float T = total[0] + nf;
    for (int i = gtid; i < llen; i += gstride) {
        int gi = gdict[i];
        uint32_t g = (uint32_t)min(max(gi, 0), nbins - 1);   // jax gather clamp
        float v = (cnts[g] + (float)bc[i >> FBITS]) / T;
        bool dec = ((uint32_t)gi < (uint32_t)nbins) && (!conflicted[g]) && (v <= 0.01f);
        if (dec) out[i] = 0.01f;
        else undecided = true;
    }
    if (undecided) atomicOr(flag, 1u);   // rare: trips the exact fallback
}

// ---- guarded exact fallback (no-op when flag==0) ----
__global__ void histG(const uint32_t* __restrict__ flag,
                      const int* __restrict__ labels,
                      const int* __restrict__ gdict,
                      unsigned int* __restrict__ slotsum, int n, int nbins) {
    if (*flag == 0u) return;
    int tid = blockIdx.x * blockDim.x + threadIdx.x;
    int stride = gridDim.x * blockDim.x;
    for (int i = tid; i < n; i += stride) {
        uint32_t g = (uint32_t)gdict[labels[i]];
        if (g < (uint32_t)nbins) atomicAdd(&slotsum[g], 1u);
    }
}

__global__ __launch_bounds__(256) void p5G(const uint32_t* __restrict__ flag,
                                           const int* __restrict__ gdict,
                                           const float* __restrict__ cnts,
                                           const uint32_t* __restrict__ slotsum,
                                           const float* __restrict__ total,
                                           float* __restrict__ out,
                                           int llen, int nbins, float nf) {
    if (*flag == 0u) return;
    int i = blockIdx.x * 256 + threadIdx.x;
    if (i >= llen) return;
    int gi = gdict[i];
    uint32_t g = (uint32_t)min(max(gi, 0), nbins - 1);
    out[i] = fmaxf((cnts[g] + (float)slotsum[g]) / (total[0] + nf), 0.01f);
}

// ---- tier-3: unconditional exact path ----
__global__ void hist_atomic(const int* __restrict__ labels,
                            const int* __restrict__ gdict,
                            unsigned int* __restrict__ ws, int n, int nbins) {
    int tid = blockIdx.x * blockDim.x + threadIdx.x;
    int stride = gridDim.x * blockDim.x;
    for (int i = tid; i < n; i += stride) {
        uint32_t g = (uint32_t)gdict[labels[i]];
        if (g < (uint32_t)nbins) atomicAdd(&ws[g], 1u);
    }
}

__global__ __launch_bounds__(256) void p5_simple(const int* __restrict__ gdict,
                                                 const float* __restrict__ cnts,
                                                 const uint32_t* __restrict__ slotsum,
                                                 const float* __restrict__ total,
                                                 float* __restrict__ out,
                                                 int llen, int nbins, float nf) {
    int i = blockIdx.x * 256 + threadIdx.x;
    if (i < llen) {
        int gi = gdict[i];
        uint32_t g = (uint32_t)min(max(gi, 0), nbins - 1);
        out[i] = fmaxf((cnts[g] + (float)slotsum[g]) / (total[0] + nf), 0.01f);
    }
}

extern "C" void kernel_launch(void* const* d_in, const int* in_sizes, int n_in,
                              void* d_out, int out_size, void* d_ws, size_t ws_size,
                              hipStream_t stream) {
    const int* gdict   = (const int*)d_in[0];
    const int* labels  = (const int*)d_in[1];
    const float* cnts  = (const float*)d_in[3];
    const float* total = (const float*)d_in[4];
    float* out = (float*)d_out;

    int llen  = in_sizes[0];
    int n     = in_sizes[1];
    int nbins = in_sizes[3];
    int nbuck = ((llen - 1) >> FBITS) + 1;
    float nf  = (float)n;

    uint8_t* ws8 = (uint8_t*)d_ws;

    // layout: [flag][bc][conflicted][slotsum][marker][pbc] — all zeroing in-kernel
    size_t o_flag = 0;
    size_t o_bc   = 256;
    size_t o_conf = align256(o_bc + (size_t)nbuck * 4);
    size_t o_slot = align256(o_conf + (size_t)nbins);
    size_t o_mark = align256(o_slot + (size_t)nbins * 4);
    size_t o_pbc  = align256(o_mark + (size_t)nbins * 4);
    size_t needed = o_pbc + (size_t)GRID_A * nbuck * 4;

    if (nbuck <= NBUCK_MAX && needed <= ws_size) {
        uint32_t* flag       = (uint32_t*)(ws8 + o_flag);
        uint32_t* bc         = (uint32_t*)(ws8 + o_bc);
        uint8_t*  conflicted = (uint8_t*)(ws8 + o_conf);
        uint32_t* slotsum    = (uint32_t*)(ws8 + o_slot);
        uint32_t* marker     = (uint32_t*)(ws8 + o_mark);
        uint32_t* pbc        = (uint32_t*)(ws8 + o_pbc);

        int lblocks = (llen + 255) / 256;

        hipLaunchKernelGGL(kA_coarse, dim3(GRID_A), dim3(256), 0, stream,
                           labels, gdict, pbc, marker, conflicted, flag,
                           n, llen, nbins, nbuck);
        hipLaunchKernelGGL(kBC, dim3(lblocks), dim3(256), 0, stream,
                           pbc, bc, gdict, marker, conflicted,
                           GRID_A, nbuck, llen, nbins);
        hipLaunchKernelGGL(kD_decide, dim3(lblocks), dim3(256), 0, stream,
                           gdict, cnts, bc, conflicted, total, out, flag, slotsum,
                           llen, nbins, nf);
        hipLaunchKernelGGL(histG, dim3(2048), dim3(256), 0, stream,
                           flag, labels, gdict, (unsigned int*)slotsum, n, nbins);
        hipLaunchKernelGGL(p5G, dim3(lblocks), dim3(256), 0, stream,
                           flag, gdict, cnts, slotsum, total, out, llen, nbins, nf);
    } else {
        uint32_t* ss = (uint32_t*)ws8;
        hipMemsetAsync(ss, 0, (size_t)nbins * 4, stream);
        hipLaunchKernelGGL(hist_atomic, dim3(2048), dim3(256), 0, stream,
                           labels, gdict, (unsigned int*)ss, n, nbins);
        hipLaunchKernelGGL(p5_simple, dim3((llen + 255) / 256), dim3(256), 0, stream,
                           gdict, cnts, ss, total, out, llen, nbins, nf);
    }
}